// Round 4
// baseline (304.770 us; speedup 1.0000x reference)
//
#include <hip/hip_runtime.h>
#include <hip/hip_bf16.h>
#include <hip/hip_fp8.h>

#define NTOK 100000
#define EPS 1e-5f

using frag  = __attribute__((ext_vector_type(8))) short;  // 8 bf16 (4 VGPR)
using f32x4 = __attribute__((ext_vector_type(4))) float;
typedef __hip_bfloat16 bf16;

__device__ inline float bits2f(unsigned int u) { union { unsigned int i; float f; } x; x.i = u; return x.f; }
__device__ inline float bf2f(unsigned short u) { return bits2f((unsigned int)u << 16); }
__device__ inline void bfu_unpack(unsigned int u, float& lo, float& hi) {
  lo = bits2f(u << 16);
  hi = bits2f(u & 0xffff0000u);
}

__device__ inline float4 fp8x4_to_f4(unsigned int u) {
  __hip_fp8_e4m3 a, b, c, d;
  a.__x = u & 0xff; b.__x = (u >> 8) & 0xff; c.__x = (u >> 16) & 0xff; d.__x = (u >> 24) & 0xff;
  return make_float4((float)a, (float)b, (float)c, (float)d);
}
__device__ inline unsigned char f_to_fp8(float f) { __hip_fp8_e4m3 t(f); return t.__x; }

__device__ inline void store_val(float* p, float v) { *p = v; }
__device__ inline void store_val(bf16* p, float v) { *p = __float2bfloat16(v); }

// ---------------------------------------------------------------------------
// fp32 -> bf16 conversions
// ---------------------------------------------------------------------------
__global__ __launch_bounds__(256) void cvt_x_kernel(const float* __restrict__ in,
                                                    bf16* __restrict__ out) {
  const int e = (blockIdx.x * 256 + threadIdx.x) * 4;
  float4 v = *(const float4*)&in[e];
  bf16 o[4] = {__float2bfloat16(v.x), __float2bfloat16(v.y),
               __float2bfloat16(v.z), __float2bfloat16(v.w)};
  *(ulong1*)&out[e] = *(ulong1*)o;
}

__global__ __launch_bounds__(256) void cvt_w_kernel(
    const float* __restrict__ w0, const float* __restrict__ w1,
    const float* __restrict__ w2, const float* __restrict__ w3,
    bf16* __restrict__ out) {
  const int e = (blockIdx.x * 256 + threadIdx.x) * 4;
  const float* src;
  int off;
  if (e < 49152)       { src = w0; off = 0; }
  else if (e < 65536)  { src = w1; off = 49152; }
  else if (e < 131072) { src = w2; off = 65536; }
  else                 { src = w3; off = 131072; }
  float4 v = *(const float4*)&src[e - off];
  bf16 o[4] = {__float2bfloat16(v.x), __float2bfloat16(v.y),
               __float2bfloat16(v.z), __float2bfloat16(v.w)};
  *(ulong1*)&out[e] = *(ulong1*)o;
}

// ---------------------------------------------------------------------------
// QKV projection: 1 wave = 64 rows x 128 cols. blockIdx.y: 0 -> q (bf16),
// 1 -> k (fp8 e4m3), 2 -> v (fp8 e4m3). Ktot = 128.
// ---------------------------------------------------------------------------
__global__ __launch_bounds__(256) void mfma_gemm_qkv(
    const bf16* __restrict__ A, const bf16* __restrict__ W,
    const float* __restrict__ bias, bf16* __restrict__ qout,
    unsigned char* __restrict__ kout, unsigned char* __restrict__ vout, int M) {
  const int lane = threadIdx.x & 63;
  const int wid = threadIdx.x >> 6;
  const int row0 = blockIdx.x * 256 + wid * 64;
  if (row0 >= M) return;
  const int cbase = blockIdx.y * 128;
  const int lr = lane & 15, kg = lane >> 4;

  f32x4 acc[4][8] = {};
  const bf16* ap[4];
#pragma unroll
  for (int i = 0; i < 4; ++i) {
    int r = row0 + 16 * i + lr;
    if (r > M - 1) r = M - 1;
    ap[i] = A + (size_t)r * 128 + kg * 8;
  }
  const bf16* wp = W + (size_t)(cbase + lr) * 128 + kg * 8;

#pragma unroll
  for (int kc = 0; kc < 128; kc += 32) {
    frag a[4];
#pragma unroll
    for (int i = 0; i < 4; ++i) a[i] = *(const frag*)(ap[i] + kc);
#pragma unroll
    for (int j = 0; j < 8; ++j) {
      frag b = *(const frag*)(wp + (size_t)16 * j * 128 + kc);
#pragma unroll
      for (int i = 0; i < 4; ++i)
        acc[i][j] = __builtin_amdgcn_mfma_f32_16x16x32_bf16(a[i], b, acc[i][j], 0, 0, 0);
    }
  }

  float bs[8];
#pragma unroll
  for (int j = 0; j < 8; ++j) bs[j] = bias[cbase + lr + 16 * j];
  const int y = blockIdx.y;
  unsigned char* f8dst = (y == 1) ? kout : vout;
#pragma unroll
  for (int i = 0; i < 4; ++i)
#pragma unroll
    for (int r = 0; r < 4; ++r) {
      const int row = row0 + 16 * i + kg * 4 + r;
      if (row >= M) continue;
      if (y == 0) {
        bf16* orow = qout + (size_t)row * 128 + lr;
#pragma unroll
        for (int j = 0; j < 8; ++j) orow[16 * j] = __float2bfloat16(acc[i][j][r] + bs[j]);
      } else {
        unsigned char* orow = f8dst + (size_t)row * 128 + lr;
#pragma unroll
        for (int j = 0; j < 8; ++j) orow[16 * j] = f_to_fp8(acc[i][j][r] + bs[j]);
      }
    }
}

// ---------------------------------------------------------------------------
// MFMA GEMM (N=128) + bias + bf16 residual + LayerNorm. 64 rows/wave.
// (used for out-proj + LN1)
// ---------------------------------------------------------------------------
template<typename OutT>
__global__ __launch_bounds__(256) void mfma_gemm_ln(
    const bf16* __restrict__ A, const bf16* __restrict__ W,
    const float* __restrict__ bias, const bf16* __restrict__ resid,
    const float* __restrict__ g, const float* __restrict__ b,
    OutT* __restrict__ out, int M, int Ktot) {
  const int lane = threadIdx.x & 63;
  const int wid = threadIdx.x >> 6;
  const int row0 = blockIdx.x * 256 + wid * 64;
  if (row0 >= M) return;
  const int lr = lane & 15, kg = lane >> 4;

  f32x4 acc[4][8] = {};
  const bf16* ap[4];
#pragma unroll
  for (int i = 0; i < 4; ++i) {
    int r = row0 + 16 * i + lr;
    if (r > M - 1) r = M - 1;
    ap[i] = A + (size_t)r * Ktot + kg * 8;
  }
  const bf16* wp = W + (size_t)lr * Ktot + kg * 8;

  for (int kc = 0; kc < Ktot; kc += 32) {
    frag a[4];
#pragma unroll
    for (int i = 0; i < 4; ++i) a[i] = *(const frag*)(ap[i] + kc);
#pragma unroll
    for (int j = 0; j < 8; ++j) {
      frag bb = *(const frag*)(wp + (size_t)16 * j * Ktot + kc);
#pragma unroll
      for (int i = 0; i < 4; ++i)
        acc[i][j] = __builtin_amdgcn_mfma_f32_16x16x32_bf16(a[i], bb, acc[i][j], 0, 0, 0);
    }
  }

  float bs[8], gs[8], bbs[8];
#pragma unroll
  for (int j = 0; j < 8; ++j) {
    const int c = lr + 16 * j;
    bs[j] = bias[c]; gs[j] = g[c]; bbs[j] = b[c];
  }

#pragma unroll
  for (int i = 0; i < 4; ++i)
#pragma unroll
    for (int r = 0; r < 4; ++r) {
      const int row = row0 + 16 * i + kg * 4 + r;
      const int rr = (row > M - 1) ? (M - 1) : row;
      const bf16* rrow = resid + (size_t)rr * 128 + lr;
      float v[8], psum = 0.f, psq = 0.f;
#pragma unroll
      for (int j = 0; j < 8; ++j) {
        v[j] = acc[i][j][r] + bs[j] + __bfloat162float(rrow[16 * j]);
        psum += v[j];
        psq += v[j] * v[j];
      }
#pragma unroll
      for (int off = 1; off < 16; off <<= 1) {
        psum += __shfl_xor(psum, off);
        psq += __shfl_xor(psq, off);
      }
      const float mean = psum * (1.f / 128.f);
      const float var = psq * (1.f / 128.f) - mean * mean;
      const float rstd = rsqrtf(var + EPS);
      if (row < M) {
        OutT* orow = out + (size_t)row * 128 + lr;
#pragma unroll
        for (int j = 0; j < 8; ++j)
          store_val(&orow[16 * j], (v[j] - mean) * rstd * gs[j] + bbs[j]);
      }
    }
}

// ---------------------------------------------------------------------------
// Fused FFN: out = LN( x1 + relu(x1 @ W1^T + b1) @ W2^T + b2 ) * g + bb
// 1 wave = 32 rows. h computed in 4 chunks of 128 cols; each chunk round-trips
// through a wave-private LDS tile (C-layout -> A-fragment layout fix), then
// immediately feeds GEMM2 against the matching W2 k-slice.
// LDS row stride 136 elems (272 B): 16B-aligned rows, uniform bank spread.
// ---------------------------------------------------------------------------
__global__ __launch_bounds__(256) void mfma_ffn_ln(
    const bf16* __restrict__ A,    // x1 [M][128]
    const bf16* __restrict__ W1,   // [512][128]
    const float* __restrict__ b1,
    const bf16* __restrict__ W2,   // [128][512]
    const float* __restrict__ b2,
    const float* __restrict__ g, const float* __restrict__ bb,
    float* __restrict__ out, int M) {
  __shared__ __align__(16) unsigned short hs[4][32][136];
  const int lane = threadIdx.x & 63;
  const int wid = threadIdx.x >> 6;
  const int row0 = blockIdx.x * 128 + wid * 32;
  if (row0 >= M) return;  // 32 | M, so waves are all-or-nothing
  const int lr = lane & 15, kg = lane >> 4;

  // persistent x1 fragments: rows row0+16i+lr, k = 32*kc + kg*8
  frag a1[2][4];
#pragma unroll
  for (int i = 0; i < 2; ++i) {
    const bf16* ap = A + (size_t)(row0 + 16 * i + lr) * 128 + kg * 8;
#pragma unroll
    for (int kc = 0; kc < 4; ++kc) a1[i][kc] = *(const frag*)(ap + 32 * kc);
  }

  f32x4 accout[2][8] = {};
#pragma unroll
  for (int cc = 0; cc < 4; ++cc) {
    // ---- GEMM1: h chunk [32][128], h-cols cc*128 .. cc*128+127
    f32x4 acch[2][8] = {};
#pragma unroll
    for (int kc = 0; kc < 4; ++kc) {
#pragma unroll
      for (int j = 0; j < 8; ++j) {
        frag b = *(const frag*)(W1 + (size_t)(cc * 128 + lr + 16 * j) * 128 + 32 * kc + kg * 8);
#pragma unroll
        for (int i = 0; i < 2; ++i)
          acch[i][j] = __builtin_amdgcn_mfma_f32_16x16x32_bf16(a1[i][kc], b, acch[i][j], 0, 0, 0);
      }
    }
    // ---- bias + relu -> LDS (C/D layout: row = 16i+4kg+r, col = lr+16j)
#pragma unroll
    for (int j = 0; j < 8; ++j) {
      const float bj = b1[cc * 128 + lr + 16 * j];
#pragma unroll
      for (int i = 0; i < 2; ++i)
#pragma unroll
        for (int r = 0; r < 4; ++r) {
          const float v = fmaxf(acch[i][j][r] + bj, 0.f);
          hs[wid][16 * i + 4 * kg + r][lr + 16 * j] =
              __bfloat16_as_ushort(__float2bfloat16(v));
        }
    }
    // ---- GEMM2: accout += h_chunk @ W2[:, cc*128 .. +127]^T
#pragma unroll
    for (int kc = 0; kc < 4; ++kc) {
      frag ah[2];
#pragma unroll
      for (int i = 0; i < 2; ++i)
        ah[i] = *(const frag*)&hs[wid][lr + 16 * i][32 * kc + kg * 8];
#pragma unroll
      for (int j = 0; j < 8; ++j) {
        frag b = *(const frag*)(W2 + (size_t)(lr + 16 * j) * 512 + cc * 128 + 32 * kc + kg * 8);
#pragma unroll
        for (int i = 0; i < 2; ++i)
          accout[i][j] = __builtin_amdgcn_mfma_f32_16x16x32_bf16(ah[i], b, accout[i][j], 0, 0, 0);
      }
    }
  }

  // ---- bias + residual + LN2 epilogue
  float bs[8], gs[8], bbs[8];
#pragma unroll
  for (int j = 0; j < 8; ++j) {
    const int c = lr + 16 * j;
    bs[j] = b2[c]; gs[j] = g[c]; bbs[j] = bb[c];
  }
#pragma unroll
  for (int i = 0; i < 2; ++i)
#pragma unroll
    for (int r = 0; r < 4; ++r) {
      const int row = row0 + 16 * i + 4 * kg + r;
      const bf16* rrow = A + (size_t)row * 128 + lr;
      float v[8], psum = 0.f, psq = 0.f;
#pragma unroll
      for (int j = 0; j < 8; ++j) {
        v[j] = accout[i][j][r] + bs[j] + __bfloat162float(rrow[16 * j]);
        psum += v[j];
        psq += v[j] * v[j];
      }
#pragma unroll
      for (int off = 1; off < 16; off <<= 1) {
        psum += __shfl_xor(psum, off);
        psq += __shfl_xor(psq, off);
      }
      const float mean = psum * (1.f / 128.f);
      const float var = psq * (1.f / 128.f) - mean * mean;
      const float rstd = rsqrtf(var + EPS);
      float* orow = out + (size_t)row * 128 + lr;
#pragma unroll
      for (int j = 0; j < 8; ++j)
        orow[16 * j] = (v[j] - mean) * rstd * gs[j] + bbs[j];
    }
}

// ---------------------------------------------------------------------------
// Sampled attention, fp8 K/V, 8B gathers (one instruction = 4 sample rows).
// Lane l: quarter qt = l>>4 (sample subset j = 4*jj+qt), lr = l&15 owns dims
// 8*lr..+7. Head = lr>>2 (4 lanes x 8 dims); score reduce shfl_xor{1,2};
// quarters merge via shfl_xor{16,32}.
// ---------------------------------------------------------------------------
__global__ __launch_bounds__(256) void attn_kernel(
    const bf16* __restrict__ qb, const unsigned char* __restrict__ kf8,
    const unsigned char* __restrict__ vf8, const int* __restrict__ samples,
    bf16* __restrict__ attn) {
  const int lane = threadIdx.x & 63;
  const int wid = threadIdx.x >> 6;
  const int tok = blockIdx.x * 4 + wid;
  if (tok >= NTOK) return;
  const int qt = lane >> 4;
  const int lr = lane & 15;

  const float scale = 0.17677669529663687f;  // 1/sqrt(32)
  float q8[8];
  {
    uint4 qu = *(const uint4*)&qb[(size_t)tok * 128 + 8 * lr];
    bfu_unpack(qu.x, q8[0], q8[1]);
    bfu_unpack(qu.y, q8[2], q8[3]);
    bfu_unpack(qu.z, q8[4], q8[5]);
    bfu_unpack(qu.w, q8[6], q8[7]);
#pragma unroll
    for (int d = 0; d < 8; ++d) q8[d] *= scale;
  }

  const int myidx = samples[tok * 16 + lr];
  int kidx[4];
#pragma unroll
  for (int jj = 0; jj < 4; ++jj) kidx[jj] = __shfl(myidx, 4 * jj + qt, 16);

  float s[4];
#pragma unroll
  for (int jj = 0; jj < 4; ++jj) {
    uint2 ku = *(const uint2*)&kf8[(size_t)kidx[jj] * 128 + 8 * lr];
    float4 k0 = fp8x4_to_f4(ku.x), k1 = fp8x4_to_f4(ku.y);
    float p = q8[0] * k0.x + q8[1] * k0.y + q8[2] * k0.z + q8[3] * k0.w +
              q8[4] * k1.x + q8[5] * k1.y + q8[6] * k1.z + q8[7] * k1.w;
    p += __shfl_xor(p, 1);
    p += __shfl_xor(p, 2);
    s[jj] = p;
  }

  float m = fmaxf(fmaxf(s[0], s[1]), fmaxf(s[2], s[3]));
  m = fmaxf(m, __shfl_xor(m, 16));
  m = fmaxf(m, __shfl_xor(m, 32));
  float sum = 0.f;
#pragma unroll
  for (int jj = 0; jj < 4; ++jj) {
    s[jj] = __expf(s[jj] - m);
    sum += s[jj];
  }
  sum += __shfl_xor(sum, 16);
  sum += __shfl_xor(sum, 32);
  const float inv = 1.f / sum;

  float a8[8] = {};
#pragma unroll
  for (int jj = 0; jj < 4; ++jj) {
    uint2 vu = *(const uint2*)&vf8[(size_t)kidx[jj] * 128 + 8 * lr];
    float4 v0 = fp8x4_to_f4(vu.x), v1 = fp8x4_to_f4(vu.y);
    const float wj = s[jj] * inv;
    a8[0] += wj * v0.x; a8[1] += wj * v0.y; a8[2] += wj * v0.z; a8[3] += wj * v0.w;
    a8[4] += wj * v1.x; a8[5] += wj * v1.y; a8[6] += wj * v1.z; a8[7] += wj * v1.w;
  }
#pragma unroll
  for (int d = 0; d < 8; ++d) {
    a8[d] += __shfl_xor(a8[d], 16);
    a8[d] += __shfl_xor(a8[d], 32);
  }

  if (qt == 0) {
    uint4 o;
    unsigned int w0 = (unsigned)__bfloat16_as_ushort(__float2bfloat16(a8[0])) |
                      ((unsigned)__bfloat16_as_ushort(__float2bfloat16(a8[1])) << 16);
    unsigned int w1 = (unsigned)__bfloat16_as_ushort(__float2bfloat16(a8[2])) |
                      ((unsigned)__bfloat16_as_ushort(__float2bfloat16(a8[3])) << 16);
    unsigned int w2 = (unsigned)__bfloat16_as_ushort(__float2bfloat16(a8[4])) |
                      ((unsigned)__bfloat16_as_ushort(__float2bfloat16(a8[5])) << 16);
    unsigned int w3 = (unsigned)__bfloat16_as_ushort(__float2bfloat16(a8[6])) |
                      ((unsigned)__bfloat16_as_ushort(__float2bfloat16(a8[7])) << 16);
    o.x = w0; o.y = w1; o.z = w2; o.w = w3;
    *(uint4*)&attn[(size_t)tok * 128 + 8 * lr] = o;
  }
}

extern "C" void kernel_launch(void* const* d_in, const int* in_sizes, int n_in,
                              void* d_out, int out_size, void* d_ws, size_t ws_size,
                              hipStream_t stream) {
  const float* x      = (const float*)d_in[0];
  const int* samples  = (const int*)d_in[1];
  const float* in_w   = (const float*)d_in[2];
  const float* in_b   = (const float*)d_in[3];
  const float* out_w  = (const float*)d_in[4];
  const float* out_b  = (const float*)d_in[5];
  const float* ffn_w1 = (const float*)d_in[6];
  const float* ffn_b1 = (const float*)d_in[7];
  const float* ffn_w2 = (const float*)d_in[8];
  const float* ffn_b2 = (const float*)d_in[9];
  const float* ln1_g  = (const float*)d_in[10];
  const float* ln1_b  = (const float*)d_in[11];
  const float* ln2_g  = (const float*)d_in[12];
  const float* ln2_b  = (const float*)d_in[13];
  float* out = (float*)d_out;

  // ws layout: xb 0 | qb 25.6M | kf8 51.2M | vf8 64M | attn 76.8M | x1b 102.4M | wb 128M
  char* ws = (char*)d_ws;
  bf16* xb   = (bf16*)(ws);
  bf16* qb   = (bf16*)(ws + 25600000);
  unsigned char* kf8 = (unsigned char*)(ws + 51200000);
  unsigned char* vf8 = (unsigned char*)(ws + 64000000);
  bf16* attn = (bf16*)(ws + 76800000);
  bf16* x1b  = (bf16*)(ws + 102400000);
  bf16* wb   = (bf16*)(ws + 128000000);
  bf16* in_wb   = wb;
  bf16* out_wb  = wb + 49152;
  bf16* ffn_w1b = wb + 65536;
  bf16* ffn_w2b = wb + 131072;

  const int M = NTOK;
  dim3 blk(256);
  const int gm = (M + 255) / 256;   // 391 (4 waves x 64 rows)
  const int gf = (M + 127) / 128;   // 782 (4 waves x 32 rows)

  cvt_x_kernel<<<dim3(12500), blk, 0, stream>>>(x, xb);
  cvt_w_kernel<<<dim3(192), blk, 0, stream>>>(in_w, out_w, ffn_w1, ffn_w2, wb);
  // 1) QKV projection -> qb (bf16), kf8/vf8 (fp8)
  mfma_gemm_qkv<<<dim3(gm, 3), blk, 0, stream>>>(xb, in_wb, in_b, qb, kf8, vf8, M);
  // 2) sampled attention -> attn (bf16)
  attn_kernel<<<dim3((M + 3) / 4), blk, 0, stream>>>(qb, kf8, vf8, samples, attn);
  // 3) out-proj + residual(xb) + LN1 -> x1b
  mfma_gemm_ln<bf16><<<dim3(gm), blk, 0, stream>>>(attn, out_wb, out_b, xb, ln1_g, ln1_b, x1b, M, 128);
  // 4+5) fused FFN1+relu+FFN2 + residual(x1b) + LN2 -> out (fp32)
  mfma_ffn_ln<<<dim3(gf), blk, 0, stream>>>(x1b, ffn_w1b, ffn_b1, ffn_w2b, ffn_b2,
                                            ln2_g, ln2_b, out, M);
}